// Round 5
// baseline (449.556 us; speedup 1.0000x reference)
//
#include <hip/hip_runtime.h>

#define MB (1ull << 20)

typedef __attribute__((ext_vector_type(8))) short bf16x8;
typedef __attribute__((ext_vector_type(4))) float f32x4;

#if defined(__has_builtin)
#if __has_builtin(__builtin_amdgcn_global_load_lds)
#define HAS_GLL 1
#endif
#endif
#ifndef HAS_GLL
#define HAS_GLL 0
#endif

__device__ __forceinline__ unsigned short f2bf(float f) {
  unsigned u = __float_as_uint(f);
  u += 0x7fffu + ((u >> 16) & 1u);
  return (unsigned short)(u >> 16);
}

#if HAS_GLL
__device__ __forceinline__ void gl16(const unsigned short* g, unsigned short* l) {
  __builtin_amdgcn_global_load_lds((const __attribute__((address_space(1))) void*)g,
                                   (__attribute__((address_space(3))) void*)l, 16, 0, 0);
}
#endif

// ---------------- fused fp32 -> bf16 convert (q,k,v in one launch) ----------------
__global__ __launch_bounds__(256) void cvt3(const float* __restrict__ x0,
                                            const float* __restrict__ x1,
                                            const float* __restrict__ x2,
                                            unsigned short* __restrict__ y0,
                                            unsigned short* __restrict__ y1,
                                            unsigned short* __restrict__ y2, int n) {
  const int z = blockIdx.y;
  const float* x = (z == 0) ? x0 : (z == 1) ? x1 : x2;
  unsigned short* y = (z == 0) ? y0 : (z == 1) ? y1 : y2;
  int i = (blockIdx.x * 256 + threadIdx.x) * 4;
  if (i >= n) return;
  float4 v = *(const float4*)(x + i);
  uint2 p;
  p.x = (unsigned)f2bf(v.x) | ((unsigned)f2bf(v.y) << 16);
  p.y = (unsigned)f2bf(v.z) | ((unsigned)f2bf(v.w) << 16);
  *(uint2*)(y + i) = p;
}

// ---------------- fused W [K][N] fp32 -> WT [N][K] bf16 (4 weights) ----------------
__global__ __launch_bounds__(256) void transpose4(const float* __restrict__ W0,
                                                  const float* __restrict__ W1,
                                                  const float* __restrict__ W2,
                                                  const float* __restrict__ W3,
                                                  unsigned short* __restrict__ T0,
                                                  unsigned short* __restrict__ T1,
                                                  unsigned short* __restrict__ T2,
                                                  unsigned short* __restrict__ T3) {
  const int z = blockIdx.z;
  const float* W = (z == 0) ? W0 : (z == 1) ? W1 : (z == 2) ? W2 : W3;
  unsigned short* WT = (z == 0) ? T0 : (z == 1) ? T1 : (z == 2) ? T2 : T3;
  __shared__ float tile[32][33];
  int bx = blockIdx.x * 32;  // n block
  int by = blockIdx.y * 32;  // k block
  int tx = threadIdx.x & 31, ty = threadIdx.x >> 5;
#pragma unroll
  for (int i = 0; i < 32; i += 8)
    tile[ty + i][tx] = W[(by + ty + i) * 1024 + bx + tx];
  __syncthreads();
#pragma unroll
  for (int i = 0; i < 32; i += 8)
    WT[(bx + ty + i) * 1024 + by + tx] = f2bf(tile[tx][ty + i]);
}

// ---------------- GEMM core: acc += A[128 x K] @ Bt[128 x K]^T ----------------
// A staged in LDS (BK=64, XOR chunk swizzle, gl16). B fragments loaded DIRECTLY
// from global (Bt is a 2 MB weight -> L2-resident; each (r,quad) group covers one
// contiguous 64B line -> zero over-fetch). B reg-loads issue between the two
// barriers so their L2 latency rides the same vmcnt drain as A's gl16.
__device__ __forceinline__ void gemm_core(const unsigned short* __restrict__ A,
                                          const unsigned short* __restrict__ Bt, int K, int m0,
                                          int n0, unsigned short* As, f32x4 (&acc)[4][4]) {
  const int tid = threadIdx.x;
  const int wave = tid >> 6, lane = tid & 63;
  const int quad = lane >> 4, r = lane & 15;
  const int wm = (wave >> 1) * 64, wn = (wave & 1) * 64;
  const int rx = r & 7;

  const int srow8 = tid >> 3;                       // 0..31 (row within 32-row slab)
  const int clog8 = ((tid & 7) ^ (srow8 & 7)) * 8;  // swizzled source chunk offset
  const unsigned short* Ag = A + (size_t)(m0 + srow8) * K + clog8;
  const unsigned short* Bg = Bt + (size_t)(n0 + wn + r) * K + quad * 8;

  const int cA = (quad ^ rx) * 8;        // ks=0 fragment chunk offset
  const int cB = ((4 ^ quad) ^ rx) * 8;  // ks=1

  for (int k0 = 0; k0 < K; k0 += 64) {
    __syncthreads();
#if HAS_GLL
#pragma unroll
    for (int s = 0; s < 4; ++s) gl16(Ag + (size_t)(s * 32) * K + k0, As + s * 2048 + tid * 8);
#else
#pragma unroll
    for (int s = 0; s < 4; ++s) {
      uint4 a = *(const uint4*)(Ag + (size_t)(s * 32) * K + k0);
      *(uint4*)(As + s * 2048 + tid * 8) = a;
    }
#endif
    bf16x8 bfr[2][4];
#pragma unroll
    for (int ks = 0; ks < 2; ++ks)
#pragma unroll
      for (int j = 0; j < 4; ++j)
        bfr[ks][j] = *(const bf16x8*)(Bg + (size_t)(j * 16) * K + k0 + ks * 32);
    __syncthreads();
#pragma unroll
    for (int ks = 0; ks < 2; ++ks) {
      const int co = ks ? cB : cA;
      bf16x8 af[4];
#pragma unroll
      for (int i = 0; i < 4; ++i) af[i] = *(const bf16x8*)(As + (wm + i * 16 + r) * 64 + co);
#pragma unroll
      for (int i = 0; i < 4; ++i)
#pragma unroll
        for (int j = 0; j < 4; ++j)
          acc[i][j] =
              __builtin_amdgcn_mfma_f32_16x16x32_bf16(af[i], bfr[ks][j], acc[i][j], 0, 0, 0);
    }
  }
}

// ---------------- fused QKV projection GEMM (grid.z selects q/k/v) ----------------
// z=0: Qb bf16 [M][N] scaled by c2; z=1: Kb bf16 [M][N]; z=2: V^T bf16 [b][N][2048]
__global__ __launch_bounds__(256) void gemm_qkv(
    const unsigned short* __restrict__ A0, const unsigned short* __restrict__ A1,
    const unsigned short* __restrict__ A2, const unsigned short* __restrict__ B0,
    const unsigned short* __restrict__ B1, const unsigned short* __restrict__ B2,
    const float* __restrict__ b0, const float* __restrict__ b1, const float* __restrict__ b2,
    unsigned short* __restrict__ O0, unsigned short* __restrict__ O1,
    unsigned short* __restrict__ O2, int M, int N, int K, float scaleQ) {
  __shared__ __align__(16) unsigned short As[128 * 64];
  const int z = blockIdx.z;
  const unsigned short* A = (z == 0) ? A0 : (z == 1) ? A1 : A2;
  const unsigned short* Bt = (z == 0) ? B0 : (z == 1) ? B1 : B2;
  const float* bias = (z == 0) ? b0 : (z == 1) ? b1 : b2;
  const float scale = (z == 0) ? scaleQ : 1.0f;
  const int m0 = blockIdx.y * 128, n0 = blockIdx.x * 128;

  f32x4 acc[4][4] = {};
  gemm_core(A, Bt, K, m0, n0, As, acc);

  const int lane = threadIdx.x & 63, wave = threadIdx.x >> 6;
  const int quad = lane >> 4, r = lane & 15;
  const int wm = (wave >> 1) * 64, wn = (wave & 1) * 64;

  if (z < 2) {
    unsigned short* Cout = (z == 0) ? O0 : O1;
#pragma unroll
    for (int i = 0; i < 4; ++i)
#pragma unroll
      for (int j = 0; j < 4; ++j) {
        const int col = n0 + wn + j * 16 + r;
        const float bv = bias[col];
#pragma unroll
        for (int t = 0; t < 4; ++t) {
          const int row = m0 + wm + i * 16 + quad * 4 + t;
          Cout[(size_t)row * N + col] = f2bf((acc[i][j][t] + bv) * scale);
        }
      }
  } else {
    // V^T store: out[(b*N + col)*2048 + row%2048], 4 contiguous rows -> b64
    const int b = m0 >> 11;
#pragma unroll
    for (int i = 0; i < 4; ++i)
#pragma unroll
      for (int j = 0; j < 4; ++j) {
        const int col = n0 + wn + j * 16 + r;
        const float bv = bias[col];
        const int rloc = (m0 & 2047) + wm + i * 16 + quad * 4;
        uint2 u;
        u.x = ((unsigned)f2bf(acc[i][j][1] + bv) << 16) | f2bf(acc[i][j][0] + bv);
        u.y = ((unsigned)f2bf(acc[i][j][3] + bv) << 16) | f2bf(acc[i][j][2] + bv);
        *(uint2*)(O2 + ((size_t)(b * N + col)) * 2048 + rloc) = u;
      }
  }
}

// ---------------- output projection GEMM, fp32 out ----------------
__global__ __launch_bounds__(256) void gemm_o(const unsigned short* __restrict__ A,
                                              const unsigned short* __restrict__ Bt,
                                              const float* __restrict__ bias,
                                              float* __restrict__ Cout, int M, int N, int K) {
  __shared__ __align__(16) unsigned short As[128 * 64];
  const int m0 = blockIdx.y * 128, n0 = blockIdx.x * 128;
  f32x4 acc[4][4] = {};
  gemm_core(A, Bt, K, m0, n0, As, acc);

  const int lane = threadIdx.x & 63, wave = threadIdx.x >> 6;
  const int quad = lane >> 4, r = lane & 15;
  const int wm = (wave >> 1) * 64, wn = (wave & 1) * 64;
#pragma unroll
  for (int i = 0; i < 4; ++i)
#pragma unroll
    for (int j = 0; j < 4; ++j) {
      const int col = n0 + wn + j * 16 + r;
      const float bv = bias[col];
#pragma unroll
      for (int t = 0; t < 4; ++t) {
        const int row = m0 + wm + i * 16 + quad * 4 + t;
        Cout[(size_t)row * N + col] = acc[i][j][t] + bv;
      }
    }
}

// ---------------- MFMA flash attention, S^T form, static-max softmax ----------------
// Round-3 phase ordering (S/exp/P-write for all jq, THEN PV for all jq -- keeps
// VGPR pressure low) + stride-64 XOR-swizzled LDS (round-4's conflict win).
// Qb: [B*S][1024] bf16 pre-scaled by log2(e)/8. Kb: [B*S][1024] bf16.
// Vt: [B][1024][2048] bf16. Ob: [B*S][1024] bf16.
// grid (8 qblocks of 256, 64 bh); 4 waves, each owns 64 q rows (4 jq of 16).
__global__ __launch_bounds__(256) void flash_mfma(const unsigned short* __restrict__ Qb,
                                                  const unsigned short* __restrict__ Kb,
                                                  const unsigned short* __restrict__ Vt,
                                                  unsigned short* __restrict__ Ob) {
  __shared__ __align__(16) unsigned short Ksh[64 * 64];     // [key][d]
  __shared__ __align__(16) unsigned short Vts[64 * 64];     // [d][key]
  __shared__ __align__(16) unsigned short Ps[4 * 64 * 64];  // per-wave [64 q][64 key]
  const int tid = threadIdx.x;
  const int wave = tid >> 6, lane = tid & 63;
  const int quad = lane >> 4, r = lane & 15;
  const int b = blockIdx.y >> 4, h = blockIdx.y & 15;
  const int qbase = b * 2048 + blockIdx.x * 256 + wave * 64;
  const int rx = r & 7;

  // Q B-fragments (lane r = q col, quad*8 = d chunk), resident all kernel
  bf16x8 qf[4][2];
#pragma unroll
  for (int jq = 0; jq < 4; ++jq)
#pragma unroll
    for (int ks = 0; ks < 2; ++ks)
      qf[jq][ks] = *(const bf16x8*)(Qb + (size_t)(qbase + jq * 16 + r) * 1024 + h * 64 +
                                    ks * 32 + quad * 8);

  f32x4 oacc[4][4] = {};  // O^T: lane q=r, d=quad*4+t (+16*dt)
  float lp[4] = {0.f, 0.f, 0.f, 0.f};

  const int srow = tid >> 2;        // staged row (key for K, d for V^T)
  const int c0 = (tid & 3) * 2;     // logical chunk pair
  const int c0p = c0 ^ (srow & 7);  // swizzled
  const unsigned short* Kg = Kb + (size_t)(b * 2048 + srow) * 1024 + h * 64 + c0 * 8;
  const unsigned short* Vg = Vt + (size_t)(b * 1024 + h * 64 + srow) * 2048 + c0 * 8;
  unsigned short* PsW = Ps + wave * 4096;

  for (int kt0 = 0; kt0 < 32; ++kt0) {
    uint4 ka = *(const uint4*)Kg;
    uint4 kb2 = *(const uint4*)(Kg + 8);
    uint4 va = *(const uint4*)Vg;
    uint4 vb2 = *(const uint4*)(Vg + 8);
    Kg += 64 * 1024;
    Vg += 64;
    __syncthreads();  // prior tile's LDS reads complete
    *(uint4*)(Ksh + srow * 64 + c0p * 8) = ka;
    *(uint4*)(Ksh + srow * 64 + (c0p ^ 1) * 8) = kb2;
    *(uint4*)(Vts + srow * 64 + c0p * 8) = va;
    *(uint4*)(Vts + srow * 64 + (c0p ^ 1) * 8) = vb2;
    __syncthreads();

    // phase 1: S^T = K·Q^T, exp2, P -> wave-private LDS (bf16)
    bf16x8 kf[4][2];
#pragma unroll
    for (int kt = 0; kt < 4; ++kt)
#pragma unroll
      for (int ks = 0; ks < 2; ++ks)
        kf[kt][ks] = *(const bf16x8*)(Ksh + (kt * 16 + r) * 64 + (((ks * 4 + quad) ^ rx) * 8));

#pragma unroll
    for (int jq = 0; jq < 4; ++jq) {
      f32x4 st[4] = {};
#pragma unroll
      for (int ks = 0; ks < 2; ++ks)
#pragma unroll
        for (int kt = 0; kt < 4; ++kt)
          st[kt] = __builtin_amdgcn_mfma_f32_16x16x32_bf16(kf[kt][ks], qf[jq][ks], st[kt], 0, 0, 0);
      // p = exp2(S*log2e/8) (scale folded into Q); no max subtraction needed
#pragma unroll
      for (int kt = 0; kt < 4; ++kt) {
        float p0 = __builtin_amdgcn_exp2f(st[kt][0]);
        float p1 = __builtin_amdgcn_exp2f(st[kt][1]);
        float p2 = __builtin_amdgcn_exp2f(st[kt][2]);
        float p3 = __builtin_amdgcn_exp2f(st[kt][3]);
        lp[jq] += (p0 + p1) + (p2 + p3);
        uint2 u;
        u.x = __builtin_amdgcn_perm(__float_as_uint(p1) + 0x8000u,
                                    __float_as_uint(p0) + 0x8000u, 0x07060302u);
        u.y = __builtin_amdgcn_perm(__float_as_uint(p3) + 0x8000u,
                                    __float_as_uint(p2) + 0x8000u, 0x07060302u);
        // P[q][key=kt*16+quad*4..+3]: chunk=(kt*2+(quad>>1))^rx, half=(quad&1)*4
        *(uint2*)(PsW + (jq * 16 + r) * 64 + (((kt * 2 + (quad >> 1)) ^ rx) * 8) +
                  (quad & 1) * 4) = u;
      }
    }

    // phase 2: O^T += V^T · P^T (wave-private Ps: no barrier, lgkmcnt only)
    bf16x8 vf[4][2];
#pragma unroll
    for (int dt = 0; dt < 4; ++dt)
#pragma unroll
      for (int ks = 0; ks < 2; ++ks)
        vf[dt][ks] = *(const bf16x8*)(Vts + (dt * 16 + r) * 64 + (((ks * 4 + quad) ^ rx) * 8));
#pragma unroll
    for (int jq = 0; jq < 4; ++jq)
#pragma unroll
      for (int ks = 0; ks < 2; ++ks) {
        bf16x8 pf = *(const bf16x8*)(PsW + (jq * 16 + r) * 64 + (((ks * 4 + quad) ^ rx) * 8));
#pragma unroll
        for (int dt = 0; dt < 4; ++dt)
          oacc[jq][dt] =
              __builtin_amdgcn_mfma_f32_16x16x32_bf16(vf[dt][ks], pf, oacc[jq][dt], 0, 0, 0);
      }
  }

  // epilogue: l over quads; O[q][d] = oacc/l (d contiguous -> b64)
#pragma unroll
  for (int jq = 0; jq < 4; ++jq) {
    float l = lp[jq];
    l += __shfl_xor(l, 16);
    l += __shfl_xor(l, 32);
    float inv = 1.0f / l;
#pragma unroll
    for (int dt = 0; dt < 4; ++dt) {
      uint2 u;
      u.x = ((unsigned)f2bf(oacc[jq][dt][1] * inv) << 16) | f2bf(oacc[jq][dt][0] * inv);
      u.y = ((unsigned)f2bf(oacc[jq][dt][3] * inv) << 16) | f2bf(oacc[jq][dt][2] * inv);
      *(uint2*)(Ob + (size_t)(qbase + jq * 16 + r) * 1024 + h * 64 + dt * 16 + quad * 4) = u;
    }
  }
}

extern "C" void kernel_launch(void* const* d_in, const int* in_sizes, int n_in, void* d_out,
                              int out_size, void* d_ws, size_t ws_size, hipStream_t stream) {
  const float* q = (const float*)d_in[0];
  const float* k = (const float*)d_in[1];
  const float* v = (const float*)d_in[2];
  const float* Wq = (const float*)d_in[3];
  const float* bq = (const float*)d_in[4];
  const float* Wk = (const float*)d_in[5];
  const float* bk = (const float*)d_in[6];
  const float* Wv = (const float*)d_in[7];
  const float* bv = (const float*)d_in[8];
  const float* Wo = (const float*)d_in[9];
  const float* bo = (const float*)d_in[10];

  unsigned char* ws = (unsigned char*)d_ws;
  unsigned short* qb = (unsigned short*)(ws + 0 * MB);
  unsigned short* kb = (unsigned short*)(ws + 16 * MB);
  unsigned short* vb = (unsigned short*)(ws + 32 * MB);
  unsigned short* WqT = (unsigned short*)(ws + 48 * MB);
  unsigned short* WkT = (unsigned short*)(ws + 50 * MB);
  unsigned short* WvT = (unsigned short*)(ws + 52 * MB);
  unsigned short* WoT = (unsigned short*)(ws + 54 * MB);
  unsigned short* Qb = (unsigned short*)(ws + 56 * MB);
  unsigned short* Kbf = (unsigned short*)(ws + 72 * MB);
  unsigned short* Vtr = (unsigned short*)(ws + 88 * MB);
  unsigned short* AOb = (unsigned short*)(ws + 104 * MB);

  const int M = 8192, D = 1024;
  const float c2 = 0.18033688011112042f;  // log2(e)/8, folded into Q

  cvt3<<<dim3(M * D / 1024, 3), 256, 0, stream>>>(q, k, v, qb, kb, vb, M * D);
  transpose4<<<dim3(32, 32, 4), 256, 0, stream>>>(Wq, Wk, Wv, Wo, WqT, WkT, WvT, WoT);

  gemm_qkv<<<dim3(D / 128, M / 128, 3), 256, 0, stream>>>(qb, kb, vb, WqT, WkT, WvT, bq, bk, bv,
                                                          Qb, Kbf, Vtr, M, D, D, c2);

  flash_mfma<<<dim3(8, 64), 256, 0, stream>>>(Qb, Kbf, Vtr, AOb);

  gemm_o<<<dim3(D / 128, M / 128), 256, 0, stream>>>(AOb, WoT, bo, (float*)d_out, M, D, D);
}

// Round 6
// 355.962 us; speedup vs baseline: 1.2629x; 1.2629x over previous
//
#include <hip/hip_runtime.h>

#define MB (1ull << 20)

typedef __attribute__((ext_vector_type(8))) short bf16x8;
typedef __attribute__((ext_vector_type(4))) float f32x4;

#if defined(__has_builtin)
#if __has_builtin(__builtin_amdgcn_global_load_lds)
#define HAS_GLL 1
#endif
#endif
#ifndef HAS_GLL
#define HAS_GLL 0
#endif

__device__ __forceinline__ unsigned short f2bf(float f) {
  unsigned u = __float_as_uint(f);
  u += 0x7fffu + ((u >> 16) & 1u);
  return (unsigned short)(u >> 16);
}

#if HAS_GLL
__device__ __forceinline__ void gl16(const unsigned short* g, unsigned short* l) {
  __builtin_amdgcn_global_load_lds((const __attribute__((address_space(1))) void*)g,
                                   (__attribute__((address_space(3))) void*)l, 16, 0, 0);
}
#endif

// ---------------- fused fp32 -> bf16 convert (q,k,v in one launch) ----------------
__global__ __launch_bounds__(256) void cvt3(const float* __restrict__ x0,
                                            const float* __restrict__ x1,
                                            const float* __restrict__ x2,
                                            unsigned short* __restrict__ y0,
                                            unsigned short* __restrict__ y1,
                                            unsigned short* __restrict__ y2, int n) {
  const int z = blockIdx.y;
  const float* x = (z == 0) ? x0 : (z == 1) ? x1 : x2;
  unsigned short* y = (z == 0) ? y0 : (z == 1) ? y1 : y2;
  int i = (blockIdx.x * 256 + threadIdx.x) * 4;
  if (i >= n) return;
  float4 v = *(const float4*)(x + i);
  uint2 p;
  p.x = (unsigned)f2bf(v.x) | ((unsigned)f2bf(v.y) << 16);
  p.y = (unsigned)f2bf(v.z) | ((unsigned)f2bf(v.w) << 16);
  *(uint2*)(y + i) = p;
}

// ---------------- fused W [K][N] fp32 -> WT [N][K] bf16 (4 weights) ----------------
__global__ __launch_bounds__(256) void transpose4(const float* __restrict__ W0,
                                                  const float* __restrict__ W1,
                                                  const float* __restrict__ W2,
                                                  const float* __restrict__ W3,
                                                  unsigned short* __restrict__ T0,
                                                  unsigned short* __restrict__ T1,
                                                  unsigned short* __restrict__ T2,
                                                  unsigned short* __restrict__ T3) {
  const int z = blockIdx.z;
  const float* W = (z == 0) ? W0 : (z == 1) ? W1 : (z == 2) ? W2 : W3;
  unsigned short* WT = (z == 0) ? T0 : (z == 1) ? T1 : (z == 2) ? T2 : T3;
  __shared__ float tile[32][33];
  int bx = blockIdx.x * 32;  // n block
  int by = blockIdx.y * 32;  // k block
  int tx = threadIdx.x & 31, ty = threadIdx.x >> 5;
#pragma unroll
  for (int i = 0; i < 32; i += 8)
    tile[ty + i][tx] = W[(by + ty + i) * 1024 + bx + tx];
  __syncthreads();
#pragma unroll
  for (int i = 0; i < 32; i += 8)
    WT[(bx + ty + i) * 1024 + by + tx] = f2bf(tile[tx][ty + i]);
}

// ---------------- GEMM core (round-4 measured-best): BK=64, XOR-swizzled LDS ----
// LDS row = 64 elems (32 words -> all banks); chunk(16B) c_phys = c_log ^ (row&7).
// Swizzle applied on the GLOBAL address so global_load_lds dest stays lane-linear.
__device__ __forceinline__ void gemm_core(const unsigned short* __restrict__ A,
                                          const unsigned short* __restrict__ Bt, int K, int m0,
                                          int n0, unsigned short* As, unsigned short* Bs,
                                          f32x4 (&acc)[4][4]) {
  const int tid = threadIdx.x;
  const int wave = tid >> 6, lane = tid & 63;
  const int quad = lane >> 4, r = lane & 15;
  const int wm = (wave >> 1) * 64, wn = (wave & 1) * 64;

  const int srow8 = tid >> 3;                       // 0..31 (row within 32-row slab)
  const int clog8 = ((tid & 7) ^ (srow8 & 7)) * 8;  // swizzled source chunk offset
  const unsigned short* Ag = A + (size_t)(m0 + srow8) * K + clog8;
  const unsigned short* Bg = Bt + (size_t)(n0 + srow8) * K + clog8;

  const int cA = ((0 ^ quad) ^ (r & 7)) * 8;  // ks=0 fragment chunk offset
  const int cB = ((4 ^ quad) ^ (r & 7)) * 8;  // ks=1

  for (int k0 = 0; k0 < K; k0 += 64) {
    __syncthreads();
#if HAS_GLL
#pragma unroll
    for (int s = 0; s < 4; ++s) {
      gl16(Ag + (size_t)(s * 32) * K + k0, As + s * 2048 + tid * 8);
      gl16(Bg + (size_t)(s * 32) * K + k0, Bs + s * 2048 + tid * 8);
    }
#else
#pragma unroll
    for (int s = 0; s < 4; ++s) {
      uint4 a = *(const uint4*)(Ag + (size_t)(s * 32) * K + k0);
      uint4 b = *(const uint4*)(Bg + (size_t)(s * 32) * K + k0);
      *(uint4*)(As + s * 2048 + tid * 8) = a;
      *(uint4*)(Bs + s * 2048 + tid * 8) = b;
    }
#endif
    __syncthreads();
#pragma unroll
    for (int ks = 0; ks < 2; ++ks) {
      const int co = ks ? cB : cA;
      bf16x8 af[4], bfr[4];
#pragma unroll
      for (int i = 0; i < 4; ++i) af[i] = *(const bf16x8*)(As + (wm + i * 16 + r) * 64 + co);
#pragma unroll
      for (int j = 0; j < 4; ++j) bfr[j] = *(const bf16x8*)(Bs + (wn + j * 16 + r) * 64 + co);
#pragma unroll
      for (int i = 0; i < 4; ++i)
#pragma unroll
        for (int j = 0; j < 4; ++j)
          acc[i][j] = __builtin_amdgcn_mfma_f32_16x16x32_bf16(af[i], bfr[j], acc[i][j], 0, 0, 0);
    }
  }
}

// ---------------- fused QKV projection GEMM (grid.z selects q/k/v) ----------------
// z=0: Qb bf16 [M][N] scaled by c2; z=1: Kb bf16 [M][N]; z=2: V^T bf16 [b][N][2048]
__global__ __launch_bounds__(256) void gemm_qkv(
    const unsigned short* __restrict__ A0, const unsigned short* __restrict__ A1,
    const unsigned short* __restrict__ A2, const unsigned short* __restrict__ B0,
    const unsigned short* __restrict__ B1, const unsigned short* __restrict__ B2,
    const float* __restrict__ b0, const float* __restrict__ b1, const float* __restrict__ b2,
    unsigned short* __restrict__ O0, unsigned short* __restrict__ O1,
    unsigned short* __restrict__ O2, int M, int N, int K, float scaleQ) {
  __shared__ __align__(16) unsigned short As[128 * 64];
  __shared__ __align__(16) unsigned short Bs[128 * 64];
  const int z = blockIdx.z;
  const unsigned short* A = (z == 0) ? A0 : (z == 1) ? A1 : A2;
  const unsigned short* Bt = (z == 0) ? B0 : (z == 1) ? B1 : B2;
  const float* bias = (z == 0) ? b0 : (z == 1) ? b1 : b2;
  const float scale = (z == 0) ? scaleQ : 1.0f;
  const int m0 = blockIdx.y * 128, n0 = blockIdx.x * 128;

  f32x4 acc[4][4] = {};
  gemm_core(A, Bt, K, m0, n0, As, Bs, acc);

  const int lane = threadIdx.x & 63, wave = threadIdx.x >> 6;
  const int quad = lane >> 4, r = lane & 15;
  const int wm = (wave >> 1) * 64, wn = (wave & 1) * 64;

  if (z < 2) {
    unsigned short* Cout = (z == 0) ? O0 : O1;
#pragma unroll
    for (int i = 0; i < 4; ++i)
#pragma unroll
      for (int j = 0; j < 4; ++j) {
        const int col = n0 + wn + j * 16 + r;
        const float bv = bias[col];
#pragma unroll
        for (int t = 0; t < 4; ++t) {
          const int row = m0 + wm + i * 16 + quad * 4 + t;
          Cout[(size_t)row * N + col] = f2bf((acc[i][j][t] + bv) * scale);
        }
      }
  } else {
    // V^T store: out[(b*N + col)*2048 + row%2048], 4 contiguous rows -> b64
    const int b = m0 >> 11;
#pragma unroll
    for (int i = 0; i < 4; ++i)
#pragma unroll
      for (int j = 0; j < 4; ++j) {
        const int col = n0 + wn + j * 16 + r;
        const float bv = bias[col];
        const int rloc = (m0 & 2047) + wm + i * 16 + quad * 4;
        uint2 u;
        u.x = ((unsigned)f2bf(acc[i][j][1] + bv) << 16) | f2bf(acc[i][j][0] + bv);
        u.y = ((unsigned)f2bf(acc[i][j][3] + bv) << 16) | f2bf(acc[i][j][2] + bv);
        *(uint2*)(O2 + ((size_t)(b * N + col)) * 2048 + rloc) = u;
      }
  }
}

// ---------------- output projection GEMM, fp32 out ----------------
__global__ __launch_bounds__(256) void gemm_o(const unsigned short* __restrict__ A,
                                              const unsigned short* __restrict__ Bt,
                                              const float* __restrict__ bias,
                                              float* __restrict__ Cout, int M, int N, int K) {
  __shared__ __align__(16) unsigned short As[128 * 64];
  __shared__ __align__(16) unsigned short Bs[128 * 64];
  const int m0 = blockIdx.y * 128, n0 = blockIdx.x * 128;
  f32x4 acc[4][4] = {};
  gemm_core(A, Bt, K, m0, n0, As, Bs, acc);

  const int lane = threadIdx.x & 63, wave = threadIdx.x >> 6;
  const int quad = lane >> 4, r = lane & 15;
  const int wm = (wave >> 1) * 64, wn = (wave & 1) * 64;
#pragma unroll
  for (int i = 0; i < 4; ++i)
#pragma unroll
    for (int j = 0; j < 4; ++j) {
      const int col = n0 + wn + j * 16 + r;
      const float bv = bias[col];
#pragma unroll
      for (int t = 0; t < 4; ++t) {
        const int row = m0 + wm + i * 16 + quad * 4 + t;
        Cout[(size_t)row * N + col] = acc[i][j][t] + bv;
      }
    }
}

// ---------------- MFMA flash attention (round-3 measured-best, verbatim) ----------------
// S^T form, static-max softmax, stride-72 padded LDS (NO xor swizzle: padded keeps
// fragment addrs affine -> compiler folds into ds_read immediate offsets, VGPR ~96).
// Qb: [B*S][1024] bf16 pre-scaled by log2(e)/8. Kb: [B*S][1024] bf16.
// Vt: [B][1024][2048] bf16. Ob: [B*S][1024] bf16.
// grid (8 qblocks of 256, 64 bh); 4 waves, each owns 64 q rows (4 jq of 16).
__global__ __launch_bounds__(256) void flash_mfma(const unsigned short* __restrict__ Qb,
                                                  const unsigned short* __restrict__ Kb,
                                                  const unsigned short* __restrict__ Vt,
                                                  unsigned short* __restrict__ Ob) {
  __shared__ __align__(16) unsigned short Ksh[64 * 72];     // [key][d] stride 72
  __shared__ __align__(16) unsigned short Vts[64 * 72];     // [d][key] stride 72
  __shared__ __align__(16) unsigned short Ps[4 * 64 * 72];  // per-wave [q][key]
  const int tid = threadIdx.x;
  const int wave = tid >> 6, lane = tid & 63;
  const int quad = lane >> 4, r = lane & 15;
  const int b = blockIdx.y >> 4, h = blockIdx.y & 15;
  const int qbase = b * 2048 + blockIdx.x * 256 + wave * 64;

  // Q B-fragments (16 q rows x 32 d per frag), resident all kernel
  bf16x8 qf[4][2];
#pragma unroll
  for (int jq = 0; jq < 4; ++jq)
#pragma unroll
    for (int ks = 0; ks < 2; ++ks)
      qf[jq][ks] = *(const bf16x8*)(Qb + (size_t)(qbase + jq * 16 + r) * 1024 + h * 64 +
                                    ks * 32 + quad * 8);

  f32x4 oacc[4][4] = {};  // O^T: lane holds q=r, d=quad*4+t (+16*dt)
  float lp[4] = {0.f, 0.f, 0.f, 0.f};

  const int srow = tid >> 2, sc = (tid & 3) * 16;
  const unsigned short* Kg = Kb + (size_t)(b * 2048 + srow) * 1024 + h * 64 + sc;
  const unsigned short* Vg = Vt + (size_t)(b * 1024 + h * 64 + srow) * 2048 + sc;
  unsigned short* PsW = Ps + wave * (64 * 72);

  for (int kt0 = 0; kt0 < 32; ++kt0) {
    uint4 ka = *(const uint4*)Kg;
    uint4 kb2 = *(const uint4*)(Kg + 8);
    uint4 va = *(const uint4*)Vg;
    uint4 vb2 = *(const uint4*)(Vg + 8);
    Kg += 64 * 1024;
    Vg += 64;
    __syncthreads();  // prior tile's LDS reads complete
    *(uint4*)(Ksh + srow * 72 + sc) = ka;
    *(uint4*)(Ksh + srow * 72 + sc + 8) = kb2;
    *(uint4*)(Vts + srow * 72 + sc) = va;
    *(uint4*)(Vts + srow * 72 + sc + 8) = vb2;
    __syncthreads();

    // phase 1: S^T = K·Q^T, exp2, P -> wave-private LDS (bf16)
    bf16x8 kf[4][2];
#pragma unroll
    for (int kt = 0; kt < 4; ++kt)
#pragma unroll
      for (int ks = 0; ks < 2; ++ks)
        kf[kt][ks] = *(const bf16x8*)(Ksh + (kt * 16 + r) * 72 + ks * 32 + quad * 8);

#pragma unroll
    for (int jq = 0; jq < 4; ++jq) {
      f32x4 st[4] = {};
#pragma unroll
      for (int ks = 0; ks < 2; ++ks)
#pragma unroll
        for (int kt = 0; kt < 4; ++kt)
          st[kt] = __builtin_amdgcn_mfma_f32_16x16x32_bf16(kf[kt][ks], qf[jq][ks], st[kt], 0, 0, 0);
      // p = exp2(S*log2e/8) (scale pre-folded into Q); no max subtraction needed
#pragma unroll
      for (int kt = 0; kt < 4; ++kt) {
        float p0 = __builtin_amdgcn_exp2f(st[kt][0]);
        float p1 = __builtin_amdgcn_exp2f(st[kt][1]);
        float p2 = __builtin_amdgcn_exp2f(st[kt][2]);
        float p3 = __builtin_amdgcn_exp2f(st[kt][3]);
        lp[jq] += (p0 + p1) + (p2 + p3);
        uint2 u;  // pack 4 keys' p as bf16
        u.x = __builtin_amdgcn_perm(__float_as_uint(p1) + 0x8000u,
                                    __float_as_uint(p0) + 0x8000u, 0x07060302u);
        u.y = __builtin_amdgcn_perm(__float_as_uint(p3) + 0x8000u,
                                    __float_as_uint(p2) + 0x8000u, 0x07060302u);
        *(uint2*)(PsW + (jq * 16 + r) * 72 + kt * 16 + quad * 4) = u;
      }
    }

    // phase 2: O^T += V^T · P^T (wave-private Ps: no barrier, lgkmcnt only)
    bf16x8 vf[4][2];
#pragma unroll
    for (int dt = 0; dt < 4; ++dt)
#pragma unroll
      for (int ks = 0; ks < 2; ++ks)
        vf[dt][ks] = *(const bf16x8*)(Vts + (dt * 16 + r) * 72 + ks * 32 + quad * 8);
#pragma unroll
    for (int jq = 0; jq < 4; ++jq)
#pragma unroll
      for (int ks = 0; ks < 2; ++ks) {
        bf16x8 pf = *(const bf16x8*)(PsW + (jq * 16 + r) * 72 + ks * 32 + quad * 8);
#pragma unroll
        for (int dt = 0; dt < 4; ++dt)
          oacc[jq][dt] =
              __builtin_amdgcn_mfma_f32_16x16x32_bf16(vf[dt][ks], pf, oacc[jq][dt], 0, 0, 0);
      }
  }

  // epilogue: l over quads; O[q][d] = oacc/l (d contiguous over t -> b64)
#pragma unroll
  for (int jq = 0; jq < 4; ++jq) {
    float l = lp[jq];
    l += __shfl_xor(l, 16);
    l += __shfl_xor(l, 32);
    float inv = 1.0f / l;
#pragma unroll
    for (int dt = 0; dt < 4; ++dt) {
      uint2 u;
      u.x = ((unsigned)f2bf(oacc[jq][dt][1] * inv) << 16) | f2bf(oacc[jq][dt][0] * inv);
      u.y = ((unsigned)f2bf(oacc[jq][dt][3] * inv) << 16) | f2bf(oacc[jq][dt][2] * inv);
      *(uint2*)(Ob + (size_t)(qbase + jq * 16 + r) * 1024 + h * 64 + dt * 16 + quad * 4) = u;
    }
  }
}

extern "C" void kernel_launch(void* const* d_in, const int* in_sizes, int n_in, void* d_out,
                              int out_size, void* d_ws, size_t ws_size, hipStream_t stream) {
  const float* q = (const float*)d_in[0];
  const float* k = (const float*)d_in[1];
  const float* v = (const float*)d_in[2];
  const float* Wq = (const float*)d_in[3];
  const float* bq = (const float*)d_in[4];
  const float* Wk = (const float*)d_in[5];
  const float* bk = (const float*)d_in[6];
  const float* Wv = (const float*)d_in[7];
  const float* bv = (const float*)d_in[8];
  const float* Wo = (const float*)d_in[9];
  const float* bo = (const float*)d_in[10];

  unsigned char* ws = (unsigned char*)d_ws;
  unsigned short* qb = (unsigned short*)(ws + 0 * MB);
  unsigned short* kb = (unsigned short*)(ws + 16 * MB);
  unsigned short* vb = (unsigned short*)(ws + 32 * MB);
  unsigned short* WqT = (unsigned short*)(ws + 48 * MB);
  unsigned short* WkT = (unsigned short*)(ws + 50 * MB);
  unsigned short* WvT = (unsigned short*)(ws + 52 * MB);
  unsigned short* WoT = (unsigned short*)(ws + 54 * MB);
  unsigned short* Qb = (unsigned short*)(ws + 56 * MB);
  unsigned short* Kbf = (unsigned short*)(ws + 72 * MB);
  unsigned short* Vtr = (unsigned short*)(ws + 88 * MB);
  unsigned short* AOb = (unsigned short*)(ws + 104 * MB);

  const int M = 8192, D = 1024;
  const float c2 = 0.18033688011112042f;  // log2(e)/8, folded into Q

  cvt3<<<dim3(M * D / 1024, 3), 256, 0, stream>>>(q, k, v, qb, kb, vb, M * D);
  transpose4<<<dim3(32, 32, 4), 256, 0, stream>>>(Wq, Wk, Wv, Wo, WqT, WkT, WvT, WoT);

  gemm_qkv<<<dim3(D / 128, M / 128, 3), 256, 0, stream>>>(qb, kb, vb, WqT, WkT, WvT, bq, bk, bv,
                                                          Qb, Kbf, Vtr, M, D, D, c2);

  flash_mfma<<<dim3(8, 64), 256, 0, stream>>>(Qb, Kbf, Vtr, AOb);

  gemm_o<<<dim3(D / 128, M / 128), 256, 0, stream>>>(AOb, WoT, bo, (float*)d_out, M, D, D);
}